// Round 8
// baseline (118.769 us; speedup 1.0000x reference)
//
#include <hip/hip_runtime.h>
#include <math.h>

#define NG 8
#define SEQ 4096
#define DM 1024
#define NE 64
#define GS (NG * SEQ)          // 32768 tokens
#define KSEL 1024              // expert capacity
#define MASK_ELEMS (NE * GS)   // 2097152
#define SEG 16
#define SEGLEN (GS / SEG)

typedef __attribute__((ext_vector_type(4))) double f64x4;

// ---------------- Kernel 1: fp64-MFMA GEMM ----------------------------------------
// A staged in LDS as f32, row stride 36 (pad): b128 writes at uniform start-banks
// (minimum LDS cycles), reads exactly 2-way (free, m136); cvt f32->f64 at read.
// B double-buffered in registers, loaded one tile EARLY so the barrier's vmcnt(0)
// drain finds them complete (kills the exposed-latency stall).
__global__ __launch_bounds__(256, 4)
void k_gemm_softmax(const float* __restrict__ x, const float* __restrict__ w,
                    const float* __restrict__ bias, const float* __restrict__ temp,
                    float* __restrict__ probsT) {
  __shared__ double S[4160];             // 33.3 KB (sized for Lt overlay)
  float* Af0 = (float*)S;                // [64][36] even tile (9 KB)
  float* Af1 = Af0 + 2304;               // odd tile
  double (*Lt)[65] = (double (*)[65])S;  // canonical logits overlay (33.3 KB)
  float  (*Pt)[68] = (float  (*)[68])S;  // transpose staging overlay (17.4 KB)

  const int tid = threadIdx.x;
  const int wid = tid >> 6, lane = tid & 63;
  const int lrow = lane & 15;
  const int lk = lane >> 4;
  const int m0 = blockIdx.x * 64;
  const int rw = wid * 16 + lrow;

  // --- self-calibration probes: D(lane,reg)->(i,j) mapping (HW-verified rnd 4) ---
  int irow[4], jcol[4];
  {
    f64x4 z4 = {0.0, 0.0, 0.0, 0.0};
    double alow = (double)lrow;
    f64x4 p1 = __builtin_amdgcn_mfma_f64_16x16x4f64(alow, 1.0, z4, 0, 0, 0);
    f64x4 p2 = __builtin_amdgcn_mfma_f64_16x16x4f64(1.0, alow, z4, 0, 0, 0);
#pragma unroll
    for (int b = 0; b < 4; ++b) {
      irow[b] = ((int)p1[b]) >> 2;
      jcol[b] = ((int)p2[b]) >> 2;
    }
  }

  f64x4 acc[4];
#pragma unroll
  for (int cb = 0; cb < 4; ++cb) acc[cb] = (f64x4){0.0, 0.0, 0.0, 0.0};

  float4 rA0, rA1;
  float bfA[8][4], bfB[8][4];                 // B regs, ping-pong per tile
  const int ar0 = tid >> 3, af4 = tid & 7;    // A staging decode

#define LOADA(t)                                                                     \
  {                                                                                  \
    const int k0_ = (t) * 32;                                                        \
    rA0 = *(const float4*)(x + (size_t)(m0 + ar0) * DM + k0_ + af4 * 4);             \
    rA1 = *(const float4*)(x + (size_t)(m0 + ar0 + 32) * DM + k0_ + af4 * 4);        \
  }

#define WRITEA(Ab)                                                                   \
  {                                                                                  \
    *(float4*)(&(Ab)[ar0 * 36 + af4 * 4]) = rA0;                                     \
    *(float4*)(&(Ab)[(ar0 + 32) * 36 + af4 * 4]) = rA1;                              \
  }

#define LOADB(t, bf)                                                                 \
  {                                                                                  \
    const int kb0_ = (t) * 32 + lk;                                                  \
    _Pragma("unroll")                                                                \
    for (int kc = 0; kc < 8; ++kc) {                                                 \
      _Pragma("unroll")                                                              \
      for (int c = 0; c < 4; ++c)                                                    \
        bf[kc][c] = w[(size_t)(kb0_ + kc * 4) * NE + c * 16 + lrow];                 \
    }                                                                                \
  }

#define MFMA_TILE(Ab, bf)                                                            \
  {                                                                                  \
    __builtin_amdgcn_s_setprio(1);                                                   \
    _Pragma("unroll")                                                                \
    for (int kc = 0; kc < 8; ++kc) {                                                 \
      double a = (double)(Ab)[rw * 36 + kc * 4 + lk];                                \
      acc[0] = __builtin_amdgcn_mfma_f64_16x16x4f64(a, (double)bf[kc][0], acc[0], 0, 0, 0); \
      acc[1] = __builtin_amdgcn_mfma_f64_16x16x4f64(a, (double)bf[kc][1], acc[1], 0, 0, 0); \
      acc[2] = __builtin_amdgcn_mfma_f64_16x16x4f64(a, (double)bf[kc][2], acc[2], 0, 0, 0); \
      acc[3] = __builtin_amdgcn_mfma_f64_16x16x4f64(a, (double)bf[kc][3], acc[3], 0, 0, 0); \
    }                                                                                \
    __builtin_amdgcn_s_setprio(0);                                                   \
  }

  LOADA(0);
  WRITEA(Af0);
  LOADA(1);
  LOADB(0, bfA);

  for (int tt = 0; tt < 32; tt += 2) {
    __syncthreads();                  // Af0 (tile tt) staged & visible
    WRITEA(Af1);                      // stage tile tt+1 (rA from last phase)
    if (tt + 2 < 32) LOADA(tt + 2);   // A prefetch: hides under MFMA below
    LOADB(tt + 1, bfB);               // EARLY B issue: hides under MFMA below
    MFMA_TILE(Af0, bfA);              // tile tt (2048 cy covers the loads)
    __syncthreads();                  // cheap: loads already complete
    if (tt + 2 < 32) {
      WRITEA(Af0);                    // stage tile tt+2
      LOADA(tt + 3);
      LOADB(tt + 2, bfA);             // EARLY B issue for tile tt+2
    }
    MFMA_TILE(Af1, bfB);              // tile tt+1
  }
  __syncthreads();                    // all MFMA reads done before Lt overlay

#undef LOADA
#undef WRITEA
#undef LOADB
#undef MFMA_TILE

  // --- canonical Lt[token_local][expert] via probe-measured mapping ---
#pragma unroll
  for (int cb = 0; cb < 4; ++cb)
#pragma unroll
    for (int b = 0; b < 4; ++b)
      Lt[wid * 16 + irow[b]][cb * 16 + jcol[b]] = acc[cb][b];
  __syncthreads();

  // --- softmax from canonical layout (fp64 logits, fp32 tail) ---
  {
    double st = (double)temp[0];
    if (st < 0.1) st = 0.1;
    const double inv_t = 1.0 / st;
    const int tt = tid >> 2, q = tid & 3;   // token tt, experts q*16..+15
    double l[16];
    double mx = -1.0e300;
#pragma unroll
    for (int j = 0; j < 16; ++j) {
      l[j] = (Lt[tt][q * 16 + j] + (double)bias[q * 16 + j]) * inv_t;
      mx = fmax(mx, l[j]);
    }
    mx = fmax(mx, __shfl_xor(mx, 1));
    mx = fmax(mx, __shfl_xor(mx, 2));
    float p[16], s = 0.0f;
#pragma unroll
    for (int j = 0; j < 16; ++j) { p[j] = __expf((float)(l[j] - mx)); s += p[j]; }
    s += __shfl_xor(s, 1);
    s += __shfl_xor(s, 2);
    const float invs = 1.0f / s;
    __syncthreads();   // all Lt reads complete before Pt overlays the same LDS
#pragma unroll
    for (int j = 0; j < 16; ++j) Pt[q * 16 + j][tt] = p[j] * invs;
  }
  __syncthreads();

  // --- coalesced expert-major store ---
  {
    const int e = tid >> 2, q = tid & 3;
#pragma unroll
    for (int c2 = 0; c2 < 4; ++c2) {
      *(float4*)(probsT + (size_t)e * GS + m0 + q * 16 + c2 * 4) =
          *(const float4*)(&Pt[e][q * 16 + c2 * 4]);
    }
  }
}

// ------------- cooperative bucket pick from a 256-bin histogram (block-wide) ------
__device__ __forceinline__ void pick_scan(const unsigned* __restrict__ bins,
                                          unsigned r_in, unsigned& bucket,
                                          unsigned& r_out, unsigned* res) {
  __syncthreads();
  const int tid = threadIdx.x;
  if (tid < 64) {
    uint4 b = ((const uint4*)bins)[tid];
    unsigned s3 = b.w, s2 = b.z + s3, s1 = b.y + s2, s0 = b.x + s1;
    unsigned suf = s0;
#pragma unroll
    for (int off = 1; off < 64; off <<= 1) {
      unsigned t = __shfl_down(suf, off);
      if (tid + off < 64) suf += t;
    }
    unsigned above = suf - s0;
    unsigned inc0 = above + s0, inc1 = above + s1, inc2 = above + s2, inc3 = above + s3;
    if (inc3 >= r_in && inc3 - b.w < r_in) { res[0] = 4 * tid + 3; res[1] = r_in - (inc3 - b.w); }
    if (inc2 >= r_in && inc2 - b.z < r_in) { res[0] = 4 * tid + 2; res[1] = r_in - (inc2 - b.z); }
    if (inc1 >= r_in && inc1 - b.y < r_in) { res[0] = 4 * tid + 1; res[1] = r_in - (inc1 - b.y); }
    if (inc0 >= r_in && inc0 - b.x < r_in) { res[0] = 4 * tid + 0; res[1] = r_in - (inc0 - b.x); }
  }
  __syncthreads();
  bucket = res[0];
  r_out = res[1];
}

// ---------------- Kernel 2: radix-select histogram pass (parallel, 1024 blocks) ---
template <int PASS>
__global__ __launch_bounds__(256)
void k_hist(const float* __restrict__ probsT, unsigned* __restrict__ ghist) {
  __shared__ unsigned h[4][256];
  __shared__ unsigned res[2];
  const int tid = threadIdx.x, wv = tid >> 6;
  const int e = blockIdx.x >> 4;
  const int seg = blockIdx.x & (SEG - 1);
  h[0][tid] = 0; h[1][tid] = 0; h[2][tid] = 0; h[3][tid] = 0;

  unsigned pfx = 0, r = KSEL;
#pragma unroll
  for (int p = 0; p < PASS; ++p) {
    unsigned b, rn;
    pick_scan(ghist + ((size_t)p * NE + e) * 256, r, b, rn, res);
    pfx |= b << (24 - 8 * p);
    r = rn;
  }
  __syncthreads();

  const unsigned hm = PASS ? (0xFFFFFFFFu << (32 - 8 * PASS)) : 0u;
  const int shift = 24 - 8 * PASS;
  const float4* col = (const float4*)(probsT + (size_t)e * GS + seg * SEGLEN);
#pragma unroll
  for (int i = 0; i < SEGLEN / 1024; ++i) {
    float4 v = col[i * 256 + tid];
    unsigned k0 = __float_as_uint(v.x), k1 = __float_as_uint(v.y);
    unsigned k2 = __float_as_uint(v.z), k3 = __float_as_uint(v.w);
    if (PASS == 0 || (k0 & hm) == pfx) atomicAdd(&h[wv][(k0 >> shift) & 255], 1u);
    if (PASS == 0 || (k1 & hm) == pfx) atomicAdd(&h[wv][(k1 >> shift) & 255], 1u);
    if (PASS == 0 || (k2 & hm) == pfx) atomicAdd(&h[wv][(k2 >> shift) & 255], 1u);
    if (PASS == 0 || (k3 & hm) == pfx) atomicAdd(&h[wv][(k3 >> shift) & 255], 1u);
  }
  __syncthreads();
  unsigned c = h[0][tid] + h[1][tid] + h[2][tid] + h[3][tid];
  if (c) atomicAdd(&ghist[((size_t)PASS * NE + e) * 256 + tid], c);
}

// ---------------- Kernel 3: tie collection (+ final pick, writes state) -----------
__global__ __launch_bounds__(256)
void k_ties(const float* __restrict__ probsT, const unsigned* __restrict__ ghist,
            uint2* __restrict__ state, unsigned* __restrict__ tiecnt,
            int* __restrict__ tiebuf) {
  __shared__ unsigned res[2];
  const int tid = threadIdx.x;
  const int e = blockIdx.x >> 4;
  const int seg = blockIdx.x & (SEG - 1);

  unsigned pfx = 0, r = KSEL;
#pragma unroll
  for (int p = 0; p < 4; ++p) {
    unsigned b, rn;
    pick_scan(ghist + ((size_t)p * NE + e) * 256, r, b, rn, res);
    pfx |= b << (24 - 8 * p);
    r = rn;
  }
  if (tid == 0 && seg == 0) state[e] = make_uint2(pfx, r);

  const float* col = probsT + (size_t)e * GS + seg * SEGLEN;
  for (int i = 0; i < SEGLEN / 256; ++i) {
    int t = i * 256 + tid;
    if (__float_as_uint(col[t]) == pfx) {
      unsigned p = atomicAdd(&tiecnt[e], 1u);
      if (p < 1024u) tiebuf[e * 1024 + p] = seg * SEGLEN + t;
    }
  }
}

// ---------------- Kernel 4: cut index = r-th smallest tie index -------------------
__global__ __launch_bounds__(256)
void k_cut(const uint2* __restrict__ state, const unsigned* __restrict__ tiecnt,
           const int* __restrict__ tiebuf, int* __restrict__ cut) {
  __shared__ int sl[1024];
  const int e = blockIdx.x, tid = threadIdx.x;
  const int cnt = (int)min(tiecnt[e], 1024u);
  const int r = (int)state[e].y;
  for (int i = tid; i < cnt; i += 256) sl[i] = tiebuf[e * 1024 + i];
  __syncthreads();
  if (r > cnt) { if (tid == 0) cut[e] = 0x7FFFFFFF; return; }
  for (int i = tid; i < cnt; i += 256) {
    int v = sl[i], rank = 0;
    for (int j = 0; j < cnt; ++j) rank += (sl[j] < v);
    if (rank == r - 1) cut[e] = v;
  }
}

// ---------------- Kernel 5: dense mask scatter + loss -----------------------------
__global__ __launch_bounds__(256)
void k_scatter(const float* __restrict__ probsT, const uint2* __restrict__ state,
               const int* __restrict__ cut, float* __restrict__ out) {
  const int gid = blockIdx.x * 256 + threadIdx.x;
  const int base = gid * 4;
  const int e = base >> 15;
  const int t = base & (GS - 1);
  float4 p = *(const float4*)(probsT + (size_t)base);
  const unsigned T = state[e].x;
  const int ct = cut[e];
  float pv[4] = {p.x, p.y, p.z, p.w};
  float mk[4], wt[4];
#pragma unroll
  for (int c = 0; c < 4; ++c) {
    unsigned key = __float_as_uint(pv[c]);
    bool sel = (key > T) || (key == T && (t + c) <= ct);
    mk[c] = sel ? 1.0f : 0.0f;
    wt[c] = sel ? pv[c] : 0.0f;
  }
  *(float4*)(out + (size_t)base) = make_float4(mk[0], mk[1], mk[2], mk[3]);
  *(float4*)(out + (size_t)MASK_ELEMS + base) = make_float4(wt[0], wt[1], wt[2], wt[3]);
  if (gid == 0) out[2 * (size_t)MASK_ELEMS] = 0.0f;
}

extern "C" void kernel_launch(void* const* d_in, const int* in_sizes, int n_in,
                              void* d_out, int out_size, void* d_ws, size_t ws_size,
                              hipStream_t stream) {
  const float* x    = (const float*)d_in[0];
  const float* gw   = (const float*)d_in[1];
  const float* gb   = (const float*)d_in[2];
  const float* temp = (const float*)d_in[3];

  float* probsT    = (float*)d_ws;
  unsigned* ghist  = (unsigned*)((char*)d_ws + (size_t)MASK_ELEMS * 4);
  unsigned* tiecnt = ghist + 4 * NE * 256;
  uint2* state     = (uint2*)(tiecnt + NE);
  int* cutp        = (int*)(state + NE);
  int* tiebuf      = cutp + NE;

  hipMemsetAsync(ghist, 0, (4 * NE * 256 + NE) * sizeof(unsigned), stream);
  k_gemm_softmax<<<GS / 64, 256, 0, stream>>>(x, gw, gb, temp, probsT);
  k_hist<0><<<NE * SEG, 256, 0, stream>>>(probsT, ghist);
  k_hist<1><<<NE * SEG, 256, 0, stream>>>(probsT, ghist);
  k_hist<2><<<NE * SEG, 256, 0, stream>>>(probsT, ghist);
  k_hist<3><<<NE * SEG, 256, 0, stream>>>(probsT, ghist);
  k_ties<<<NE * SEG, 256, 0, stream>>>(probsT, ghist, state, tiecnt, tiebuf);
  k_cut<<<NE, 256, 0, stream>>>(state, tiecnt, tiebuf, cutp);
  k_scatter<<<MASK_ELEMS / 1024, 256, 0, stream>>>(probsT, state, cutp, (float*)d_out);
}

// Round 9
// 112.039 us; speedup vs baseline: 1.0601x; 1.0601x over previous
//
#include <hip/hip_runtime.h>
#include <math.h>

#define NG 8
#define SEQ 4096
#define DM 1024
#define NE 64
#define GS (NG * SEQ)          // 32768 tokens
#define KSEL 1024              // expert capacity
#define MASK_ELEMS (NE * GS)   // 2097152
#define SEG 16
#define SEGLEN (GS / SEG)

typedef __attribute__((ext_vector_type(4))) double f64x4;

// ---------------- Kernel 1: fp64-MFMA GEMM, BARRIER-FREE 1-wave blocks ------------
// Each 64-thread block = ONE wave computing a 16-token x 64-expert tile. The wave
// stages its own A-tile (f32, stride-36: frag reads 2-way = free) -> only lgkmcnt
// ordering, no s_barrier, no vmcnt(0) drains. B double-buffered in registers
// (L2-hot w, immediate-offset scalar loads). ~8 independent wave-blocks/CU
// free-run: one wave's MFMA covers another's staging.
__global__ __launch_bounds__(64, 2)
void k_gemm_softmax(const float* __restrict__ x, const float* __restrict__ w,
                    const float* __restrict__ bias, const float* __restrict__ temp,
                    float* __restrict__ probsT) {
  __shared__ double Lt[16][65];      // canonical logits (8.3 KB)
  __shared__ float Af[2][16][36];    // A tiles, ping-pong (4.6 KB)
  __shared__ float Pt[64][20];       // transpose staging (5.1 KB)

  const int lane = threadIdx.x;
  const int lrow = lane & 15;        // A-row / B-col / frag row
  const int lk = lane >> 4;          // k-offset within k-group
  const int m0 = blockIdx.x * 16;

  // --- self-calibration probes: D(lane,reg)->(i,j) mapping (HW-verified rnd 4) ---
  int irow[4], jcol[4];
  {
    f64x4 z4 = {0.0, 0.0, 0.0, 0.0};
    double alow = (double)lrow;
    f64x4 p1 = __builtin_amdgcn_mfma_f64_16x16x4f64(alow, 1.0, z4, 0, 0, 0);
    f64x4 p2 = __builtin_amdgcn_mfma_f64_16x16x4f64(1.0, alow, z4, 0, 0, 0);
#pragma unroll
    for (int b = 0; b < 4; ++b) {
      irow[b] = ((int)p1[b]) >> 2;
      jcol[b] = ((int)p2[b]) >> 2;
    }
  }

  f64x4 acc[4];
#pragma unroll
  for (int cb = 0; cb < 4; ++cb) acc[cb] = (f64x4){0.0, 0.0, 0.0, 0.0};

  float4 rA0, rA1;                       // A prefetch regs (16 rows x 32 k / 64 ln)
  float bfA[32], bfB[32];                // B regs [kc*4+c], ping-pong per tile
  const int arow = lane >> 2, af = lane & 3;   // A staging decode

#define LOADA(t)                                                                     \
  {                                                                                  \
    const float* ap = x + (size_t)(m0 + arow) * DM + (t) * 32 + af * 8;              \
    rA0 = *(const float4*)ap;                                                        \
    rA1 = *(const float4*)(ap + 4);                                                  \
  }

#define WRITEA(bi)                                                                   \
  {                                                                                  \
    *(float4*)(&Af[bi][arow][af * 8]) = rA0;                                         \
    *(float4*)(&Af[bi][arow][af * 8 + 4]) = rA1;                                     \
  }

#define LOADB(t, bf)                                                                 \
  {                                                                                  \
    const float* bp = w + (size_t)((t) * 32 + lk) * NE + lrow;                       \
    _Pragma("unroll")                                                                \
    for (int kc = 0; kc < 8; ++kc) {                                                 \
      _Pragma("unroll")                                                              \
      for (int c = 0; c < 4; ++c)                                                    \
        bf[kc * 4 + c] = bp[kc * 4 * NE + c * 16];                                   \
    }                                                                                \
  }

#define MFMA_TILE(bi, bf)                                                            \
  {                                                                                  \
    __builtin_amdgcn_s_setprio(1);                                                   \
    _Pragma("unroll")                                                                \
    for (int kc = 0; kc < 8; ++kc) {                                                 \
      double a = (double)Af[bi][lrow][kc * 4 + lk];                                  \
      acc[0] = __builtin_amdgcn_mfma_f64_16x16x4f64(a, (double)bf[kc * 4 + 0], acc[0], 0, 0, 0); \
      acc[1] = __builtin_amdgcn_mfma_f64_16x16x4f64(a, (double)bf[kc * 4 + 1], acc[1], 0, 0, 0); \
      acc[2] = __builtin_amdgcn_mfma_f64_16x16x4f64(a, (double)bf[kc * 4 + 2], acc[2], 0, 0, 0); \
      acc[3] = __builtin_amdgcn_mfma_f64_16x16x4f64(a, (double)bf[kc * 4 + 3], acc[3], 0, 0, 0); \
    }                                                                                \
    __builtin_amdgcn_s_setprio(0);                                                   \
  }

  LOADA(0);
  WRITEA(0);          // waits vmcnt for rA, then ds_write
  LOADA(1);           // reissue into same regs (after WRITEA consumed them)
  LOADB(0, bfA);

  for (int tt = 0; tt < 32; tt += 2) {
    WRITEA(1);                       // stage A(tt+1) from rA
    if (tt + 2 < 32) LOADA(tt + 2);  // global prefetch, hides under MFMA
    LOADB(tt + 1, bfB);              // B prefetch, hides under MFMA
    MFMA_TILE(0, bfA);               // tile tt (2048 cy)
    if (tt + 2 < 32) {
      WRITEA(0);                     // stage A(tt+2)
      LOADA(tt + 3);
      LOADB(tt + 2, bfA);
    }
    MFMA_TILE(1, bfB);               // tile tt+1
  }

#undef LOADA
#undef WRITEA
#undef LOADB
#undef MFMA_TILE

  // --- canonical Lt[token_local][expert] via probe-measured mapping (1 wave: only
  // lgkmcnt ordering needed, compiler inserts it) ---
#pragma unroll
  for (int cb = 0; cb < 4; ++cb)
#pragma unroll
    for (int b = 0; b < 4; ++b)
      Lt[irow[b]][cb * 16 + jcol[b]] = acc[cb][b];

  // --- softmax from canonical layout (fp64 logits, fp32 tail) ---
  {
    double st = (double)temp[0];
    if (st < 0.1) st = 0.1;
    const double inv_t = 1.0 / st;
    const int tt = lane >> 2, q = lane & 3;   // token tt (0..15), experts q*16..+15
    double l[16];
    double mx = -1.0e300;
#pragma unroll
    for (int j = 0; j < 16; ++j) {
      l[j] = (Lt[tt][q * 16 + j] + (double)bias[q * 16 + j]) * inv_t;
      mx = fmax(mx, l[j]);
    }
    mx = fmax(mx, __shfl_xor(mx, 1));
    mx = fmax(mx, __shfl_xor(mx, 2));
    float p[16], s = 0.0f;
#pragma unroll
    for (int j = 0; j < 16; ++j) { p[j] = __expf((float)(l[j] - mx)); s += p[j]; }
    s += __shfl_xor(s, 1);
    s += __shfl_xor(s, 2);
    const float invs = 1.0f / s;
#pragma unroll
    for (int j = 0; j < 16; ++j) Pt[q * 16 + j][tt] = p[j] * invs;
  }

  // --- expert-major store: lane = expert, 16 f32 per expert ---
  {
#pragma unroll
    for (int c2 = 0; c2 < 4; ++c2) {
      *(float4*)(probsT + (size_t)lane * GS + m0 + c2 * 4) =
          *(const float4*)(&Pt[lane][c2 * 4]);
    }
  }
}

// ------------- cooperative bucket pick from a 256-bin histogram (block-wide) ------
__device__ __forceinline__ void pick_scan(const unsigned* __restrict__ bins,
                                          unsigned r_in, unsigned& bucket,
                                          unsigned& r_out, unsigned* res) {
  __syncthreads();
  const int tid = threadIdx.x;
  if (tid < 64) {
    uint4 b = ((const uint4*)bins)[tid];
    unsigned s3 = b.w, s2 = b.z + s3, s1 = b.y + s2, s0 = b.x + s1;
    unsigned suf = s0;
#pragma unroll
    for (int off = 1; off < 64; off <<= 1) {
      unsigned t = __shfl_down(suf, off);
      if (tid + off < 64) suf += t;
    }
    unsigned above = suf - s0;
    unsigned inc0 = above + s0, inc1 = above + s1, inc2 = above + s2, inc3 = above + s3;
    if (inc3 >= r_in && inc3 - b.w < r_in) { res[0] = 4 * tid + 3; res[1] = r_in - (inc3 - b.w); }
    if (inc2 >= r_in && inc2 - b.z < r_in) { res[0] = 4 * tid + 2; res[1] = r_in - (inc2 - b.z); }
    if (inc1 >= r_in && inc1 - b.y < r_in) { res[0] = 4 * tid + 1; res[1] = r_in - (inc1 - b.y); }
    if (inc0 >= r_in && inc0 - b.x < r_in) { res[0] = 4 * tid + 0; res[1] = r_in - (inc0 - b.x); }
  }
  __syncthreads();
  bucket = res[0];
  r_out = res[1];
}

// ---------------- Kernel 2: radix-select histogram pass (parallel, 1024 blocks) ---
template <int PASS>
__global__ __launch_bounds__(256)
void k_hist(const float* __restrict__ probsT, unsigned* __restrict__ ghist) {
  __shared__ unsigned h[4][256];
  __shared__ unsigned res[2];
  const int tid = threadIdx.x, wv = tid >> 6;
  const int e = blockIdx.x >> 4;
  const int seg = blockIdx.x & (SEG - 1);
  h[0][tid] = 0; h[1][tid] = 0; h[2][tid] = 0; h[3][tid] = 0;

  unsigned pfx = 0, r = KSEL;
#pragma unroll
  for (int p = 0; p < PASS; ++p) {
    unsigned b, rn;
    pick_scan(ghist + ((size_t)p * NE + e) * 256, r, b, rn, res);
    pfx |= b << (24 - 8 * p);
    r = rn;
  }
  __syncthreads();

  const unsigned hm = PASS ? (0xFFFFFFFFu << (32 - 8 * PASS)) : 0u;
  const int shift = 24 - 8 * PASS;
  const float4* col = (const float4*)(probsT + (size_t)e * GS + seg * SEGLEN);
#pragma unroll
  for (int i = 0; i < SEGLEN / 1024; ++i) {
    float4 v = col[i * 256 + tid];
    unsigned k0 = __float_as_uint(v.x), k1 = __float_as_uint(v.y);
    unsigned k2 = __float_as_uint(v.z), k3 = __float_as_uint(v.w);
    if (PASS == 0 || (k0 & hm) == pfx) atomicAdd(&h[wv][(k0 >> shift) & 255], 1u);
    if (PASS == 0 || (k1 & hm) == pfx) atomicAdd(&h[wv][(k1 >> shift) & 255], 1u);
    if (PASS == 0 || (k2 & hm) == pfx) atomicAdd(&h[wv][(k2 >> shift) & 255], 1u);
    if (PASS == 0 || (k3 & hm) == pfx) atomicAdd(&h[wv][(k3 >> shift) & 255], 1u);
  }
  __syncthreads();
  unsigned c = h[0][tid] + h[1][tid] + h[2][tid] + h[3][tid];
  if (c) atomicAdd(&ghist[((size_t)PASS * NE + e) * 256 + tid], c);
}

// ---------------- Kernel 3: tie collection (+ final pick, writes state) -----------
__global__ __launch_bounds__(256)
void k_ties(const float* __restrict__ probsT, const unsigned* __restrict__ ghist,
            uint2* __restrict__ state, unsigned* __restrict__ tiecnt,
            int* __restrict__ tiebuf) {
  __shared__ unsigned res[2];
  const int tid = threadIdx.x;
  const int e = blockIdx.x >> 4;
  const int seg = blockIdx.x & (SEG - 1);

  unsigned pfx = 0, r = KSEL;
#pragma unroll
  for (int p = 0; p < 4; ++p) {
    unsigned b, rn;
    pick_scan(ghist + ((size_t)p * NE + e) * 256, r, b, rn, res);
    pfx |= b << (24 - 8 * p);
    r = rn;
  }
  if (tid == 0 && seg == 0) state[e] = make_uint2(pfx, r);

  const float* col = probsT + (size_t)e * GS + seg * SEGLEN;
  for (int i = 0; i < SEGLEN / 256; ++i) {
    int t = i * 256 + tid;
    if (__float_as_uint(col[t]) == pfx) {
      unsigned p = atomicAdd(&tiecnt[e], 1u);
      if (p < 1024u) tiebuf[e * 1024 + p] = seg * SEGLEN + t;
    }
  }
}

// ---------------- Kernel 4: cut index = r-th smallest tie index -------------------
__global__ __launch_bounds__(256)
void k_cut(const uint2* __restrict__ state, const unsigned* __restrict__ tiecnt,
           const int* __restrict__ tiebuf, int* __restrict__ cut) {
  __shared__ int sl[1024];
  const int e = blockIdx.x, tid = threadIdx.x;
  const int cnt = (int)min(tiecnt[e], 1024u);
  const int r = (int)state[e].y;
  for (int i = tid; i < cnt; i += 256) sl[i] = tiebuf[e * 1024 + i];
  __syncthreads();
  if (r > cnt) { if (tid == 0) cut[e] = 0x7FFFFFFF; return; }
  for (int i = tid; i < cnt; i += 256) {
    int v = sl[i], rank = 0;
    for (int j = 0; j < cnt; ++j) rank += (sl[j] < v);
    if (rank == r - 1) cut[e] = v;
  }
}

// ---------------- Kernel 5: dense mask scatter + loss -----------------------------
__global__ __launch_bounds__(256)
void k_scatter(const float* __restrict__ probsT, const uint2* __restrict__ state,
               const int* __restrict__ cut, float* __restrict__ out) {
  const int gid = blockIdx.x * 256 + threadIdx.x;
  const int base = gid * 4;
  const int e = base >> 15;
  const int t = base & (GS - 1);
  float4 p = *(const float4*)(probsT + (size_t)base);
  const unsigned T = state[e].x;
  const int ct = cut[e];
  float pv[4] = {p.x, p.y, p.z, p.w};
  float mk[4], wt[4];
#pragma unroll
  for (int c = 0; c < 4; ++c) {
    unsigned key = __float_as_uint(pv[c]);
    bool sel = (key > T) || (key == T && (t + c) <= ct);
    mk[c] = sel ? 1.0f : 0.0f;
    wt[c] = sel ? pv[c] : 0.0f;
  }
  *(float4*)(out + (size_t)base) = make_float4(mk[0], mk[1], mk[2], mk[3]);
  *(float4*)(out + (size_t)MASK_ELEMS + base) = make_float4(wt[0], wt[1], wt[2], wt[3]);
  if (gid == 0) out[2 * (size_t)MASK_ELEMS] = 0.0f;
}

extern "C" void kernel_launch(void* const* d_in, const int* in_sizes, int n_in,
                              void* d_out, int out_size, void* d_ws, size_t ws_size,
                              hipStream_t stream) {
  const float* x    = (const float*)d_in[0];
  const float* gw   = (const float*)d_in[1];
  const float* gb   = (const float*)d_in[2];
  const float* temp = (const float*)d_in[3];

  float* probsT    = (float*)d_ws;
  unsigned* ghist  = (unsigned*)((char*)d_ws + (size_t)MASK_ELEMS * 4);
  unsigned* tiecnt = ghist + 4 * NE * 256;
  uint2* state     = (uint2*)(tiecnt + NE);
  int* cutp        = (int*)(state + NE);
  int* tiebuf      = cutp + NE;

  hipMemsetAsync(ghist, 0, (4 * NE * 256 + NE) * sizeof(unsigned), stream);
  k_gemm_softmax<<<GS / 16, 64, 0, stream>>>(x, gw, gb, temp, probsT);
  k_hist<0><<<NE * SEG, 256, 0, stream>>>(probsT, ghist);
  k_hist<1><<<NE * SEG, 256, 0, stream>>>(probsT, ghist);
  k_hist<2><<<NE * SEG, 256, 0, stream>>>(probsT, ghist);
  k_hist<3><<<NE * SEG, 256, 0, stream>>>(probsT, ghist);
  k_ties<<<NE * SEG, 256, 0, stream>>>(probsT, ghist, state, tiecnt, tiebuf);
  k_cut<<<NE, 256, 0, stream>>>(state, tiecnt, tiebuf, cutp);
  k_scatter<<<MASK_ELEMS / 1024, 256, 0, stream>>>(probsT, state, cutp, (float*)d_out);
}